// Round 4
// baseline (1331.778 us; speedup 1.0000x reference)
//
#include <hip/hip_runtime.h>

// R-GCN layer: out[v] = sum_{e: dst[e]=v} norm[e] * (h[src[e]] @ W[rel[e]])
//
// R4: two throughput phases instead of latency-bound (dst,rel) micro-buckets:
//   A) dense GEMM pnr[r][n][:] = h @ W[r] in bf16, permuted row layout so each
//      wave stores coalesced dwordx2 (no LDS transpose). Write-BW bound.
//   B) edges bucketed by dst-block (782). One wave per edge: coalesced 128B
//      pnr-row read, scale by norm, one ds_add_f32 into LDS tile, out written
//      once. Independent iterations -> full memory-level parallelism.
// Relations processed in np chunks sized from ws_size (chunk stays L3-resident
// between A and B).

#define NNODES 50000
#define NPAD   50048
#define NEDGES 1600000
#define NRELS  32
#define NBLK   782
#define HIST_BLOCKS 782      // 782*2048 >= 1.6M

typedef __attribute__((ext_vector_type(8))) __bf16 bf16x8;
typedef __attribute__((ext_vector_type(4))) __bf16 bf16x4;
typedef __attribute__((ext_vector_type(4))) float f32x4;

__global__ __launch_bounds__(256) void k_zero(int4* __restrict__ p, int n4) {
    int i = blockIdx.x * 256 + threadIdx.x;
    if (i < n4) p[i] = make_int4(0, 0, 0, 0);
}

#define PREP_H_BLOCKS 1564   // 1564*256 = 400384 = NPAD*8
__global__ __launch_bounds__(256) void k_prep(const float* __restrict__ h,
                                              const float* __restrict__ W,
                                              bf16x8* __restrict__ hb8,
                                              bf16x8* __restrict__ wf8) {
    int b = blockIdx.x;
    if (b < PREP_H_BLOCKS) {
        int i = b * 256 + threadIdx.x;          // 8-float group, < NPAD*8
        bf16x8 v;
        #pragma unroll
        for (int j = 0; j < 8; ++j) v[j] = (__bf16)0.f;
        if (i < NNODES * 8) {
            const float4* hp = (const float4*)h;
            float4 a0 = hp[(size_t)i * 2];
            float4 a1 = hp[(size_t)i * 2 + 1];
            v[0] = (__bf16)a0.x; v[1] = (__bf16)a0.y; v[2] = (__bf16)a0.z; v[3] = (__bf16)a0.w;
            v[4] = (__bf16)a1.x; v[5] = (__bf16)a1.y; v[6] = (__bf16)a1.z; v[7] = (__bf16)a1.w;
        }
        hb8[i] = v;
    } else {
        int i = (b - PREP_H_BLOCKS) * 256 + threadIdx.x;   // 0..16383
        int lane = i & 63, frag = i >> 6;                  // frag = (r*2+kt)*4+nt
        int nt = frag & 3, kt = (frag >> 2) & 1, r = frag >> 3;
        int m = lane & 15, q = lane >> 4;
        const float* Wr = W + (size_t)r * 64 * 64;
        bf16x8 v;
        #pragma unroll
        for (int j = 0; j < 8; ++j)
            v[j] = (__bf16)Wr[(kt * 32 + q * 8 + j) * 64 + nt * 16 + m];
        wf8[i] = v;
    }
}

__global__ __launch_bounds__(256) void k_hist(const int* __restrict__ dst,
                                              const int* __restrict__ rel,
                                              int* __restrict__ g_count,
                                              int np, int rcshift) {
    int e = blockIdx.x * 2048 + threadIdx.x;
    #pragma unroll
    for (int rnd = 0; rnd < 8; ++rnd, e += 256) {
        if (e < NEDGES) {
            int key = (dst[e] >> 6) * np + (rel[e] >> rcshift);
            atomicAdd(&g_count[key], 1);
        }
    }
}

__global__ __launch_bounds__(256) void k_scan(const int* __restrict__ g_count,
                                              int* __restrict__ g_base,
                                              int* __restrict__ g_cursor, int NBG) {
    __shared__ int wt[4];
    __shared__ int wbase[4];
    const int t = threadIdx.x, lane = t & 63, wid = t >> 6;
    const int PER = (NBG + 255) / 256;
    int lo = t * PER;
    int hi = min(lo + PER, NBG);
    int s = 0;
    for (int i = lo; i < hi; ++i) s += g_count[i];
    int incl = s;
    #pragma unroll
    for (int d = 1; d < 64; d <<= 1) {
        int v = __shfl_up(incl, d, 64);
        if (lane >= d) incl += v;
    }
    if (lane == 63) wt[wid] = incl;
    __syncthreads();
    if (t == 0) { int a = 0; for (int i = 0; i < 4; ++i) { wbase[i] = a; a += wt[i]; } }
    __syncthreads();
    int excl = wbase[wid] + incl - s;
    for (int i = lo; i < hi; ++i) {
        g_base[i] = excl;
        g_cursor[i] = excl;
        excl += g_count[i];
    }
}

__global__ __launch_bounds__(256) void k_scatter(
        const int* __restrict__ src, const int* __restrict__ dst,
        const int* __restrict__ rel, const float* __restrict__ norm,
        int* __restrict__ g_cursor, int2* __restrict__ bpack,
        int np, int rcshift) {
    int e = blockIdx.x * 2048 + threadIdx.x;
    #pragma unroll
    for (int rnd = 0; rnd < 8; ++rnd, e += 256) {
        if (e < NEDGES) {
            int d = dst[e], r = rel[e];
            int key = (d >> 6) * np + (r >> rcshift);
            int pos = atomicAdd(&g_cursor[key], 1);
            int rloc = r & ((1 << rcshift) - 1);
            bpack[pos] = make_int2((src[e] & 0xFFFF) | ((d & 63) << 16) | (rloc << 22),
                                   __float_as_int(norm[e]));
        }
    }
}

// Phase A: pnr[rloc][n][p] bf16, permuted cols p = m*4+nt <-> o = nt*16+m.
__global__ __launch_bounds__(256) void k_gemmA(const bf16x8* __restrict__ hb8,
        const bf16x8* __restrict__ wf8, char* __restrict__ pnr,
        int c, int RC, int RCB) {
    const int w = threadIdx.x >> 6, lane = threadIdx.x & 63;
    const int m = lane & 15, q = lane >> 4;
    const int n0 = blockIdx.x * 64 + w * 16;
    const int r0 = c * RC + blockIdx.y * RCB;

    bf16x8 a0 = hb8[(size_t)(n0 + m) * 8 + q];        // A[m][k], k = q*8+j
    bf16x8 a1 = hb8[(size_t)(n0 + m) * 8 + 4 + q];    // k = 32 + q*8+j

    for (int rr = 0; rr < RCB; ++rr) {
        const int r = r0 + rr;
        const int rloc = r - c * RC;
        bf16x8 Bf0[4], Bf1[4];
        #pragma unroll
        for (int nt = 0; nt < 4; ++nt) {
            Bf0[nt] = wf8[(size_t)((r * 2 + 0) * 4 + nt) * 64 + lane];
            Bf1[nt] = wf8[(size_t)((r * 2 + 1) * 4 + nt) * 64 + lane];
        }
        f32x4 acc[4];
        #pragma unroll
        for (int nt = 0; nt < 4; ++nt) acc[nt] = (f32x4){0.f, 0.f, 0.f, 0.f};
        #pragma unroll
        for (int nt = 0; nt < 4; ++nt)
            acc[nt] = __builtin_amdgcn_mfma_f32_16x16x32_bf16(a0, Bf0[nt], acc[nt], 0, 0, 0);
        #pragma unroll
        for (int nt = 0; nt < 4; ++nt)
            acc[nt] = __builtin_amdgcn_mfma_f32_16x16x32_bf16(a1, Bf1[nt], acc[nt], 0, 0, 0);
        // C row = q*4+reg (node), col o = nt*16+m. Lane's 4 nt-values for one
        // row are contiguous at p = m*4+nt -> one 8B store per reg, coalesced.
        #pragma unroll
        for (int reg = 0; reg < 4; ++reg) {
            int nst = n0 + q * 4 + reg;
            if (nst < NNODES) {
                bf16x4 v;
                v[0] = (__bf16)acc[0][reg]; v[1] = (__bf16)acc[1][reg];
                v[2] = (__bf16)acc[2][reg]; v[3] = (__bf16)acc[3][reg];
                *(bf16x4*)(pnr + (size_t)(rloc * NNODES + nst) * 128 + m * 8) = v;
            }
        }
    }
}

// Phase B: one wave per edge; lane L reads permuted element p=L of the pnr row,
// true col = (L&3)*16 + (L>>2); ds_add into LDS tile (row uniform, col bijective).
__global__ __launch_bounds__(512) void k_seg(const unsigned short* __restrict__ pnr,
        const int2* __restrict__ bpack, const int* __restrict__ g_base,
        const int* __restrict__ g_count, float* __restrict__ out,
        int c, int np, int accum) {
    __shared__ float accs[4096];
    __shared__ int2 meta[8][64];
    for (int i = threadIdx.x; i < 4096; i += 512) accs[i] = 0.f;
    __syncthreads();
    const int wv = threadIdx.x >> 6, lane = threadIdx.x & 63;
    const int col = ((lane & 3) << 4) | (lane >> 2);
    const int bkt = blockIdx.x * np + c;
    const int cnt = g_count[bkt];
    const int base = g_base[bkt];

    for (int i0 = wv * 64; i0 < cnt; i0 += 512) {
        int idx = i0 + lane;
        int2 pk = make_int2(0, 0);            // invalid lanes: norm=0 -> adds 0
        if (idx < cnt) pk = bpack[base + idx];
        meta[wv][lane] = pk;
        #pragma unroll 16
        for (int j = 0; j < 64; ++j) {
            int2 md = meta[wv][j];            // same addr all lanes: broadcast
            int x = md.x;
            float nrm = __int_as_float(md.y);
            int s = x & 0xFFFF;
            int row = (x >> 16) & 63;
            int rloc = (x >> 22) & 31;
            float v = __int_as_float(((int)pnr[((size_t)(rloc * NNODES + s)) * 64 + lane]) << 16);
            atomicAdd(&accs[(row << 6) | col], v * nrm);
        }
    }
    __syncthreads();
    const int node0 = blockIdx.x * 64;
    for (int i = threadIdx.x; i < 4096; i += 512) {
        int node = node0 + (i >> 6);
        if (node < NNODES) {
            size_t o = (size_t)node * 64 + (i & 63);
            if (accum) out[o] += accs[i];
            else out[o] = accs[i];
        }
    }
}

extern "C" void kernel_launch(void* const* d_in, const int* in_sizes, int n_in,
                              void* d_out, int out_size, void* d_ws, size_t ws_size,
                              hipStream_t stream) {
    const float* h    = (const float*)d_in[0];
    const float* W    = (const float*)d_in[1];
    const int*   src  = (const int*)d_in[2];
    const int*   dst  = (const int*)d_in[3];
    const int*   rel  = (const int*)d_in[4];
    const float* norm = (const float*)d_in[5];
    float* out = (float*)d_out;

    // Pick relation-chunk count np (prefer 2: 102.4 MB pnr chunk, L3-resident).
    int np;
    size_t o_bpack = 0, o_hb = 0, o_wf = 0, o_pnr = 0;
    for (np = 2;; np *= 2) {
        int nbg = NBLK * np;
        size_t o = ((size_t)3 * nbg * 4 + 255) & ~(size_t)255;
        o_bpack = o; o += (size_t)NEDGES * 8;
        o_hb    = o; o += (size_t)NPAD * 8 * 16;
        o_wf    = o; o += (size_t)16384 * 16;
        o_pnr   = o; o += (size_t)(NRELS / np) * NNODES * 128;
        if (o <= ws_size || np == 32) break;
    }
    const int RC = NRELS / np;
    int rcshift = 0; while ((1 << rcshift) < RC) ++rcshift;
    const int RCB = RC < 8 ? RC : 8;
    const int SPLIT = RC / RCB;
    const int NBG = NBLK * np;

    char* ws = (char*)d_ws;
    int* g_count  = (int*)ws;
    int* g_base   = g_count + NBG;
    int* g_cursor = g_count + 2 * NBG;
    int2* bpack   = (int2*)(ws + o_bpack);
    bf16x8* hb8   = (bf16x8*)(ws + o_hb);
    bf16x8* wf8   = (bf16x8*)(ws + o_wf);
    char* pnr     = ws + o_pnr;

    int n4 = (3 * NBG * 4 + 15) / 16;
    k_zero<<<(n4 + 255) / 256, 256, 0, stream>>>((int4*)g_count, n4);
    k_prep<<<PREP_H_BLOCKS + 64, 256, 0, stream>>>(h, W, hb8, wf8);
    k_hist<<<HIST_BLOCKS, 256, 0, stream>>>(dst, rel, g_count, np, rcshift);
    k_scan<<<1, 256, 0, stream>>>(g_count, g_base, g_cursor, NBG);
    k_scatter<<<HIST_BLOCKS, 256, 0, stream>>>(src, dst, rel, norm, g_cursor, bpack, np, rcshift);
    for (int c = 0; c < np; ++c) {
        dim3 ga(NBLK, SPLIT);
        k_gemmA<<<ga, 256, 0, stream>>>(hb8, wf8, pnr, c, RC, RCB);
        k_seg<<<NBLK, 512, 0, stream>>>((const unsigned short*)pnr, bpack,
                                        g_base, g_count, out, c, np, c > 0 ? 1 : 0);
    }
}

// Round 5
// 1322.613 us; speedup vs baseline: 1.0069x; 1.0069x over previous
//
#include <hip/hip_runtime.h>

// R-GCN layer: out[v] = sum_{e: dst[e]=v} norm[e] * (h[src[e]] @ W[rel[e]])
//
// R5: same two-phase structure as R4 (dense GEMM pnr = h@W[r] in bf16 with
// permuted coalesced layout; then dst-block bucketed scatter-sum), but k_seg's
// inner loop is restructured for memory-level parallelism:
//  - per-edge meta broadcast via readlane (SGPRs, no LDS buffer)
//  - explicit 8-deep batches: 8 independent global ushort loads in flight
//    before any use (R4's compiled form had ~1 in flight -> latency-bound,
//    VGPR_Count=12 was the tell)

#define NNODES 50000
#define NPAD   50048
#define NEDGES 1600000
#define NRELS  32
#define NBLK   782
#define HIST_BLOCKS 782      // 782*2048 >= 1.6M

typedef __attribute__((ext_vector_type(8))) __bf16 bf16x8;
typedef __attribute__((ext_vector_type(4))) __bf16 bf16x4;
typedef __attribute__((ext_vector_type(4))) float f32x4;

__global__ __launch_bounds__(256) void k_zero(int4* __restrict__ p, int n4) {
    int i = blockIdx.x * 256 + threadIdx.x;
    if (i < n4) p[i] = make_int4(0, 0, 0, 0);
}

#define PREP_H_BLOCKS 1564   // 1564*256 = 400384 = NPAD*8
__global__ __launch_bounds__(256) void k_prep(const float* __restrict__ h,
                                              const float* __restrict__ W,
                                              bf16x8* __restrict__ hb8,
                                              bf16x8* __restrict__ wf8) {
    int b = blockIdx.x;
    if (b < PREP_H_BLOCKS) {
        int i = b * 256 + threadIdx.x;          // 8-float group, < NPAD*8
        bf16x8 v;
        #pragma unroll
        for (int j = 0; j < 8; ++j) v[j] = (__bf16)0.f;
        if (i < NNODES * 8) {
            const float4* hp = (const float4*)h;
            float4 a0 = hp[(size_t)i * 2];
            float4 a1 = hp[(size_t)i * 2 + 1];
            v[0] = (__bf16)a0.x; v[1] = (__bf16)a0.y; v[2] = (__bf16)a0.z; v[3] = (__bf16)a0.w;
            v[4] = (__bf16)a1.x; v[5] = (__bf16)a1.y; v[6] = (__bf16)a1.z; v[7] = (__bf16)a1.w;
        }
        hb8[i] = v;
    } else {
        int i = (b - PREP_H_BLOCKS) * 256 + threadIdx.x;   // 0..16383
        int lane = i & 63, frag = i >> 6;                  // frag = (r*2+kt)*4+nt
        int nt = frag & 3, kt = (frag >> 2) & 1, r = frag >> 3;
        int m = lane & 15, q = lane >> 4;
        const float* Wr = W + (size_t)r * 64 * 64;
        bf16x8 v;
        #pragma unroll
        for (int j = 0; j < 8; ++j)
            v[j] = (__bf16)Wr[(kt * 32 + q * 8 + j) * 64 + nt * 16 + m];
        wf8[i] = v;
    }
}

__global__ __launch_bounds__(256) void k_hist(const int* __restrict__ dst,
                                              const int* __restrict__ rel,
                                              int* __restrict__ g_count,
                                              int np, int rcshift) {
    int e = blockIdx.x * 2048 + threadIdx.x;
    #pragma unroll
    for (int rnd = 0; rnd < 8; ++rnd, e += 256) {
        if (e < NEDGES) {
            int key = (dst[e] >> 6) * np + (rel[e] >> rcshift);
            atomicAdd(&g_count[key], 1);
        }
    }
}

__global__ __launch_bounds__(256) void k_scan(const int* __restrict__ g_count,
                                              int* __restrict__ g_base,
                                              int* __restrict__ g_cursor, int NBG) {
    __shared__ int wt[4];
    __shared__ int wbase[4];
    const int t = threadIdx.x, lane = t & 63, wid = t >> 6;
    const int PER = (NBG + 255) / 256;
    int lo = t * PER;
    int hi = min(lo + PER, NBG);
    int s = 0;
    for (int i = lo; i < hi; ++i) s += g_count[i];
    int incl = s;
    #pragma unroll
    for (int d = 1; d < 64; d <<= 1) {
        int v = __shfl_up(incl, d, 64);
        if (lane >= d) incl += v;
    }
    if (lane == 63) wt[wid] = incl;
    __syncthreads();
    if (t == 0) { int a = 0; for (int i = 0; i < 4; ++i) { wbase[i] = a; a += wt[i]; } }
    __syncthreads();
    int excl = wbase[wid] + incl - s;
    for (int i = lo; i < hi; ++i) {
        g_base[i] = excl;
        g_cursor[i] = excl;
        excl += g_count[i];
    }
}

__global__ __launch_bounds__(256) void k_scatter(
        const int* __restrict__ src, const int* __restrict__ dst,
        const int* __restrict__ rel, const float* __restrict__ norm,
        int* __restrict__ g_cursor, int2* __restrict__ bpack,
        int np, int rcshift) {
    int e = blockIdx.x * 2048 + threadIdx.x;
    #pragma unroll
    for (int rnd = 0; rnd < 8; ++rnd, e += 256) {
        if (e < NEDGES) {
            int d = dst[e], r = rel[e];
            int key = (d >> 6) * np + (r >> rcshift);
            int pos = atomicAdd(&g_cursor[key], 1);
            int rloc = r & ((1 << rcshift) - 1);
            bpack[pos] = make_int2((src[e] & 0xFFFF) | ((d & 63) << 16) | (rloc << 22),
                                   __float_as_int(norm[e]));
        }
    }
}

// Phase A: pnr[rloc][n][p] bf16, permuted cols p = m*4+nt <-> o = nt*16+m.
__global__ __launch_bounds__(256) void k_gemmA(const bf16x8* __restrict__ hb8,
        const bf16x8* __restrict__ wf8, char* __restrict__ pnr,
        int c, int RC, int RCB) {
    const int w = threadIdx.x >> 6, lane = threadIdx.x & 63;
    const int m = lane & 15, q = lane >> 4;
    const int n0 = blockIdx.x * 64 + w * 16;
    const int r0 = c * RC + blockIdx.y * RCB;

    bf16x8 a0 = hb8[(size_t)(n0 + m) * 8 + q];        // A[m][k], k = q*8+j
    bf16x8 a1 = hb8[(size_t)(n0 + m) * 8 + 4 + q];    // k = 32 + q*8+j

    for (int rr = 0; rr < RCB; ++rr) {
        const int r = r0 + rr;
        const int rloc = r - c * RC;
        bf16x8 Bf0[4], Bf1[4];
        #pragma unroll
        for (int nt = 0; nt < 4; ++nt) {
            Bf0[nt] = wf8[(size_t)((r * 2 + 0) * 4 + nt) * 64 + lane];
            Bf1[nt] = wf8[(size_t)((r * 2 + 1) * 4 + nt) * 64 + lane];
        }
        f32x4 acc[4];
        #pragma unroll
        for (int nt = 0; nt < 4; ++nt) acc[nt] = (f32x4){0.f, 0.f, 0.f, 0.f};
        #pragma unroll
        for (int nt = 0; nt < 4; ++nt)
            acc[nt] = __builtin_amdgcn_mfma_f32_16x16x32_bf16(a0, Bf0[nt], acc[nt], 0, 0, 0);
        #pragma unroll
        for (int nt = 0; nt < 4; ++nt)
            acc[nt] = __builtin_amdgcn_mfma_f32_16x16x32_bf16(a1, Bf1[nt], acc[nt], 0, 0, 0);
        // C row = q*4+reg (node), col o = nt*16+m -> contiguous at p = m*4+nt.
        #pragma unroll
        for (int reg = 0; reg < 4; ++reg) {
            int nst = n0 + q * 4 + reg;
            if (nst < NNODES) {
                bf16x4 v;
                v[0] = (__bf16)acc[0][reg]; v[1] = (__bf16)acc[1][reg];
                v[2] = (__bf16)acc[2][reg]; v[3] = (__bf16)acc[3][reg];
                *(bf16x4*)(pnr + (size_t)(rloc * NNODES + nst) * 128 + m * 8) = v;
            }
        }
    }
}

// Phase B: one wave per edge-op; meta broadcast via readlane (scalar), 8-deep
// explicit load batches for MLP; ds_add into LDS tile (row scalar, col
// bijective -> conflict-free); out written once.
__global__ __launch_bounds__(512) void k_seg(const unsigned short* __restrict__ pnr,
        const int2* __restrict__ bpack, const int* __restrict__ g_base,
        const int* __restrict__ g_count, float* __restrict__ out,
        int c, int np, int accum) {
    __shared__ float accs[4096];
    for (int i = threadIdx.x; i < 4096; i += 512) accs[i] = 0.f;
    __syncthreads();
    const int wv = threadIdx.x >> 6, lane = threadIdx.x & 63;
    const int col = ((lane & 3) << 4) | (lane >> 2);   // true col for perm elem p=lane
    const int bkt = blockIdx.x * np + c;
    const int cnt = g_count[bkt];
    const int base = g_base[bkt];

    for (int i0 = wv * 64; i0 < cnt; i0 += 512) {
        int idx = i0 + lane;
        int2 pk = make_int2(0, 0);           // invalid lanes: norm = 0 -> adds 0
        if (idx < cnt) pk = bpack[base + idx];
        #pragma unroll
        for (int jb = 0; jb < 64; jb += 8) {
            unsigned short val[8];
            int adr[8];
            float nrm[8];
            #pragma unroll
            for (int u = 0; u < 8; ++u) {
                int x = __builtin_amdgcn_readlane(pk.x, jb + u);
                int y = __builtin_amdgcn_readlane(pk.y, jb + u);
                int s = x & 0xFFFF;
                int rloc = (x >> 22) & 31;
                val[u] = pnr[((size_t)(rloc * NNODES + s) << 6) | lane];
                adr[u] = (((x >> 16) & 63) << 6) | col;
                nrm[u] = __int_as_float(y);
            }
            #pragma unroll
            for (int u = 0; u < 8; ++u) {
                float v = __int_as_float(((int)val[u]) << 16) * nrm[u];
                atomicAdd(&accs[adr[u]], v);
            }
        }
    }
    __syncthreads();
    const int node0 = blockIdx.x * 64;
    for (int i = threadIdx.x; i < 4096; i += 512) {
        int node = node0 + (i >> 6);
        if (node < NNODES) {
            size_t o = (size_t)node * 64 + (i & 63);
            if (accum) out[o] += accs[i];
            else out[o] = accs[i];
        }
    }
}

extern "C" void kernel_launch(void* const* d_in, const int* in_sizes, int n_in,
                              void* d_out, int out_size, void* d_ws, size_t ws_size,
                              hipStream_t stream) {
    const float* h    = (const float*)d_in[0];
    const float* W    = (const float*)d_in[1];
    const int*   src  = (const int*)d_in[2];
    const int*   dst  = (const int*)d_in[3];
    const int*   rel  = (const int*)d_in[4];
    const float* norm = (const float*)d_in[5];
    float* out = (float*)d_out;

    // Pick relation-chunk count np (prefer 2: 102.4 MB pnr chunk, L3-resident).
    int np;
    size_t o_bpack = 0, o_hb = 0, o_wf = 0, o_pnr = 0;
    for (np = 2;; np *= 2) {
        int nbg = NBLK * np;
        size_t o = ((size_t)3 * nbg * 4 + 255) & ~(size_t)255;
        o_bpack = o; o += (size_t)NEDGES * 8;
        o_hb    = o; o += (size_t)NPAD * 8 * 16;
        o_wf    = o; o += (size_t)16384 * 16;
        o_pnr   = o; o += (size_t)(NRELS / np) * NNODES * 128;
        if (o <= ws_size || np == 32) break;
    }
    const int RC = NRELS / np;
    int rcshift = 0; while ((1 << rcshift) < RC) ++rcshift;
    const int RCB = RC < 8 ? RC : 8;
    const int SPLIT = RC / RCB;
    const int NBG = NBLK * np;

    char* ws = (char*)d_ws;
    int* g_count  = (int*)ws;
    int* g_base   = g_count + NBG;
    int* g_cursor = g_count + 2 * NBG;
    int2* bpack   = (int2*)(ws + o_bpack);
    bf16x8* hb8   = (bf16x8*)(ws + o_hb);
    bf16x8* wf8   = (bf16x8*)(ws + o_wf);
    char* pnr     = ws + o_pnr;

    int n4 = (3 * NBG * 4 + 15) / 16;
    k_zero<<<(n4 + 255) / 256, 256, 0, stream>>>((int4*)g_count, n4);
    k_prep<<<PREP_H_BLOCKS + 64, 256, 0, stream>>>(h, W, hb8, wf8);
    k_hist<<<HIST_BLOCKS, 256, 0, stream>>>(dst, rel, g_count, np, rcshift);
    k_scan<<<1, 256, 0, stream>>>(g_count, g_base, g_cursor, NBG);
    k_scatter<<<HIST_BLOCKS, 256, 0, stream>>>(src, dst, rel, norm, g_cursor, bpack, np, rcshift);
    for (int c = 0; c < np; ++c) {
        dim3 ga(NBLK, SPLIT);
        k_gemmA<<<ga, 256, 0, stream>>>(hb8, wf8, pnr, c, RC, RCB);
        k_seg<<<NBLK, 512, 0, stream>>>((const unsigned short*)pnr, bpack,
                                        g_base, g_count, out, c, np, c > 0 ? 1 : 0);
    }
}

// Round 6
// 720.636 us; speedup vs baseline: 1.8481x; 1.8353x over previous
//
#include <hip/hip_runtime.h>

// R-GCN layer: out[v] = sum_{e: dst[e]=v} norm[e] * (h[src[e]] @ W[rel[e]])
//
// R6: two-phase (A: pnr = h@W[r] bf16 permuted; B: dst-block scatter-sum).
// k_seg rewritten: LDS fp32 atomics measured at ~275 cyc per wave-wide ds_add
// (~4.3 cyc/lane, serialized) across R2-R5 -- they were the wall. Now each
// wave owns a private 64x64 f32 LDS tile (4 waves x 16 KB = 64 KB) and does
// ordered non-atomic ds_read+add+ds_write (same-wave DS ordering => safe;
// disjoint tiles => no cross-wave races). Cross-wave reduce at the end.

#define NNODES 50000
#define NPAD   50048
#define NEDGES 1600000
#define NRELS  32
#define NBLK   782
#define HIST_BLOCKS 782      // 782*2048 >= 1.6M

typedef __attribute__((ext_vector_type(8))) __bf16 bf16x8;
typedef __attribute__((ext_vector_type(4))) __bf16 bf16x4;
typedef __attribute__((ext_vector_type(4))) float f32x4;

__global__ __launch_bounds__(256) void k_zero(int4* __restrict__ p, int n4) {
    int i = blockIdx.x * 256 + threadIdx.x;
    if (i < n4) p[i] = make_int4(0, 0, 0, 0);
}

#define PREP_H_BLOCKS 1564   // 1564*256 = 400384 = NPAD*8
__global__ __launch_bounds__(256) void k_prep(const float* __restrict__ h,
                                              const float* __restrict__ W,
                                              bf16x8* __restrict__ hb8,
                                              bf16x8* __restrict__ wf8) {
    int b = blockIdx.x;
    if (b < PREP_H_BLOCKS) {
        int i = b * 256 + threadIdx.x;          // 8-float group, < NPAD*8
        bf16x8 v;
        #pragma unroll
        for (int j = 0; j < 8; ++j) v[j] = (__bf16)0.f;
        if (i < NNODES * 8) {
            const float4* hp = (const float4*)h;
            float4 a0 = hp[(size_t)i * 2];
            float4 a1 = hp[(size_t)i * 2 + 1];
            v[0] = (__bf16)a0.x; v[1] = (__bf16)a0.y; v[2] = (__bf16)a0.z; v[3] = (__bf16)a0.w;
            v[4] = (__bf16)a1.x; v[5] = (__bf16)a1.y; v[6] = (__bf16)a1.z; v[7] = (__bf16)a1.w;
        }
        hb8[i] = v;
    } else {
        int i = (b - PREP_H_BLOCKS) * 256 + threadIdx.x;   // 0..16383
        int lane = i & 63, frag = i >> 6;                  // frag = (r*2+kt)*4+nt
        int nt = frag & 3, kt = (frag >> 2) & 1, r = frag >> 3;
        int m = lane & 15, q = lane >> 4;
        const float* Wr = W + (size_t)r * 64 * 64;
        bf16x8 v;
        #pragma unroll
        for (int j = 0; j < 8; ++j)
            v[j] = (__bf16)Wr[(kt * 32 + q * 8 + j) * 64 + nt * 16 + m];
        wf8[i] = v;
    }
}

__global__ __launch_bounds__(256) void k_hist(const int* __restrict__ dst,
                                              const int* __restrict__ rel,
                                              int* __restrict__ g_count,
                                              int np, int rcshift) {
    int e = blockIdx.x * 2048 + threadIdx.x;
    #pragma unroll
    for (int rnd = 0; rnd < 8; ++rnd, e += 256) {
        if (e < NEDGES) {
            int key = (dst[e] >> 6) * np + (rel[e] >> rcshift);
            atomicAdd(&g_count[key], 1);
        }
    }
}

__global__ __launch_bounds__(256) void k_scan(const int* __restrict__ g_count,
                                              int* __restrict__ g_base,
                                              int* __restrict__ g_cursor, int NBG) {
    __shared__ int wt[4];
    __shared__ int wbase[4];
    const int t = threadIdx.x, lane = t & 63, wid = t >> 6;
    const int PER = (NBG + 255) / 256;
    int lo = t * PER;
    int hi = min(lo + PER, NBG);
    int s = 0;
    for (int i = lo; i < hi; ++i) s += g_count[i];
    int incl = s;
    #pragma unroll
    for (int d = 1; d < 64; d <<= 1) {
        int v = __shfl_up(incl, d, 64);
        if (lane >= d) incl += v;
    }
    if (lane == 63) wt[wid] = incl;
    __syncthreads();
    if (t == 0) { int a = 0; for (int i = 0; i < 4; ++i) { wbase[i] = a; a += wt[i]; } }
    __syncthreads();
    int excl = wbase[wid] + incl - s;
    for (int i = lo; i < hi; ++i) {
        g_base[i] = excl;
        g_cursor[i] = excl;
        excl += g_count[i];
    }
}

__global__ __launch_bounds__(256) void k_scatter(
        const int* __restrict__ src, const int* __restrict__ dst,
        const int* __restrict__ rel, const float* __restrict__ norm,
        int* __restrict__ g_cursor, int2* __restrict__ bpack,
        int np, int rcshift) {
    int e = blockIdx.x * 2048 + threadIdx.x;
    #pragma unroll
    for (int rnd = 0; rnd < 8; ++rnd, e += 256) {
        if (e < NEDGES) {
            int d = dst[e], r = rel[e];
            int key = (d >> 6) * np + (r >> rcshift);
            int pos = atomicAdd(&g_cursor[key], 1);
            int rloc = r & ((1 << rcshift) - 1);
            bpack[pos] = make_int2((src[e] & 0xFFFF) | ((d & 63) << 16) | (rloc << 22),
                                   __float_as_int(norm[e]));
        }
    }
}

// Phase A: pnr[rloc][n][p] bf16, permuted cols p = m*4+nt <-> o = nt*16+m.
__global__ __launch_bounds__(256) void k_gemmA(const bf16x8* __restrict__ hb8,
        const bf16x8* __restrict__ wf8, char* __restrict__ pnr,
        int c, int RC, int RCB) {
    const int w = threadIdx.x >> 6, lane = threadIdx.x & 63;
    const int m = lane & 15, q = lane >> 4;
    const int n0 = blockIdx.x * 64 + w * 16;
    const int r0 = c * RC + blockIdx.y * RCB;

    bf16x8 a0 = hb8[(size_t)(n0 + m) * 8 + q];        // A[m][k], k = q*8+j
    bf16x8 a1 = hb8[(size_t)(n0 + m) * 8 + 4 + q];    // k = 32 + q*8+j

    for (int rr = 0; rr < RCB; ++rr) {
        const int r = r0 + rr;
        const int rloc = r - c * RC;
        bf16x8 Bf0[4], Bf1[4];
        #pragma unroll
        for (int nt = 0; nt < 4; ++nt) {
            Bf0[nt] = wf8[(size_t)((r * 2 + 0) * 4 + nt) * 64 + lane];
            Bf1[nt] = wf8[(size_t)((r * 2 + 1) * 4 + nt) * 64 + lane];
        }
        f32x4 acc[4];
        #pragma unroll
        for (int nt = 0; nt < 4; ++nt) acc[nt] = (f32x4){0.f, 0.f, 0.f, 0.f};
        #pragma unroll
        for (int nt = 0; nt < 4; ++nt)
            acc[nt] = __builtin_amdgcn_mfma_f32_16x16x32_bf16(a0, Bf0[nt], acc[nt], 0, 0, 0);
        #pragma unroll
        for (int nt = 0; nt < 4; ++nt)
            acc[nt] = __builtin_amdgcn_mfma_f32_16x16x32_bf16(a1, Bf1[nt], acc[nt], 0, 0, 0);
        // C row = q*4+reg (node), col o = nt*16+m -> contiguous at p = m*4+nt.
        #pragma unroll
        for (int reg = 0; reg < 4; ++reg) {
            int nst = n0 + q * 4 + reg;
            if (nst < NNODES) {
                bf16x4 v;
                v[0] = (__bf16)acc[0][reg]; v[1] = (__bf16)acc[1][reg];
                v[2] = (__bf16)acc[2][reg]; v[3] = (__bf16)acc[3][reg];
                *(bf16x4*)(pnr + (size_t)(rloc * NNODES + nst) * 128 + m * 8) = v;
            }
        }
    }
}

// Phase B: 4 waves/block, per-wave-private 64x64 f32 LDS tile, non-atomic
// ordered RMW. Meta broadcast via readlane; 8-deep gather batches for MLP.
__global__ __launch_bounds__(256) void k_seg(const unsigned short* __restrict__ pnr,
        const int2* __restrict__ bpack, const int* __restrict__ g_base,
        const int* __restrict__ g_count, float* __restrict__ out,
        int c, int np, int accum) {
    __shared__ float tiles[4][4096];   // 64 KB: 2 blocks/CU
    for (int i = threadIdx.x; i < 4096; i += 256)
        ((float4*)tiles)[i] = make_float4(0.f, 0.f, 0.f, 0.f);
    __syncthreads();
    const int wv = threadIdx.x >> 6, lane = threadIdx.x & 63;
    const int col = ((lane & 3) << 4) | (lane >> 2);   // true col for perm elem p=lane
    float* tile = tiles[wv];
    const int bkt = blockIdx.x * np + c;
    const int cnt = g_count[bkt];
    const int base = g_base[bkt];

    for (int i0 = wv * 64; i0 < cnt; i0 += 256) {
        int idx = i0 + lane;
        int2 pk = make_int2(0, 0);           // invalid lanes: norm = 0 -> adds 0
        if (idx < cnt) pk = bpack[base + idx];
        #pragma unroll
        for (int jb = 0; jb < 64; jb += 8) {
            unsigned short val[8];
            int row[8];
            float nrm[8];
            #pragma unroll
            for (int u = 0; u < 8; ++u) {
                int x = __builtin_amdgcn_readlane(pk.x, jb + u);
                int y = __builtin_amdgcn_readlane(pk.y, jb + u);
                int s = x & 0xFFFF;
                int rloc = (x >> 22) & 31;
                val[u] = pnr[((size_t)(rloc * NNODES + s) << 6) | lane];
                row[u] = (x >> 16) & 63;
                nrm[u] = __int_as_float(y);
            }
            #pragma unroll
            for (int u = 0; u < 8; ++u) {
                float v = __int_as_float(((int)val[u]) << 16) * nrm[u];
                tile[(row[u] << 6) | col] += v;   // ds_read+add+ds_write, same-wave ordered
            }
        }
    }
    __syncthreads();
    const int node0 = blockIdx.x * 64;
    for (int i = threadIdx.x; i < 4096; i += 256) {
        int node = node0 + (i >> 6);
        if (node < NNODES) {
            float s = tiles[0][i] + tiles[1][i] + tiles[2][i] + tiles[3][i];
            size_t o = (size_t)node * 64 + (i & 63);
            out[o] = accum ? out[o] + s : s;
        }
    }
}

extern "C" void kernel_launch(void* const* d_in, const int* in_sizes, int n_in,
                              void* d_out, int out_size, void* d_ws, size_t ws_size,
                              hipStream_t stream) {
    const float* h    = (const float*)d_in[0];
    const float* W    = (const float*)d_in[1];
    const int*   src  = (const int*)d_in[2];
    const int*   dst  = (const int*)d_in[3];
    const int*   rel  = (const int*)d_in[4];
    const float* norm = (const float*)d_in[5];
    float* out = (float*)d_out;

    // Pick relation-chunk count np (prefer 2: 102.4 MB pnr chunk, L3-resident).
    int np;
    size_t o_bpack = 0, o_hb = 0, o_wf = 0, o_pnr = 0;
    for (np = 2;; np *= 2) {
        int nbg = NBLK * np;
        size_t o = ((size_t)3 * nbg * 4 + 255) & ~(size_t)255;
        o_bpack = o; o += (size_t)NEDGES * 8;
        o_hb    = o; o += (size_t)NPAD * 8 * 16;
        o_wf    = o; o += (size_t)16384 * 16;
        o_pnr   = o; o += (size_t)(NRELS / np) * NNODES * 128;
        if (o <= ws_size || np == 32) break;
    }
    const int RC = NRELS / np;
    int rcshift = 0; while ((1 << rcshift) < RC) ++rcshift;
    const int RCB = RC < 8 ? RC : 8;
    const int SPLIT = RC / RCB;
    const int NBG = NBLK * np;

    char* ws = (char*)d_ws;
    int* g_count  = (int*)ws;
    int* g_base   = g_count + NBG;
    int* g_cursor = g_count + 2 * NBG;
    int2* bpack   = (int2*)(ws + o_bpack);
    bf16x8* hb8   = (bf16x8*)(ws + o_hb);
    bf16x8* wf8   = (bf16x8*)(ws + o_wf);
    char* pnr     = ws + o_pnr;

    int n4 = (3 * NBG * 4 + 15) / 16;
    k_zero<<<(n4 + 255) / 256, 256, 0, stream>>>((int4*)g_count, n4);
    k_prep<<<PREP_H_BLOCKS + 64, 256, 0, stream>>>(h, W, hb8, wf8);
    k_hist<<<HIST_BLOCKS, 256, 0, stream>>>(dst, rel, g_count, np, rcshift);
    k_scan<<<1, 256, 0, stream>>>(g_count, g_base, g_cursor, NBG);
    k_scatter<<<HIST_BLOCKS, 256, 0, stream>>>(src, dst, rel, norm, g_cursor, bpack, np, rcshift);
    for (int c = 0; c < np; ++c) {
        dim3 ga(NBLK, SPLIT);
        k_gemmA<<<ga, 256, 0, stream>>>(hb8, wf8, pnr, c, RC, RCB);
        k_seg<<<NBLK, 256, 0, stream>>>((const unsigned short*)pnr, bpack,
                                        g_base, g_count, out, c, np, c > 0 ? 1 : 0);
    }
}